// Round 1
// 865.913 us; speedup vs baseline: 1.0825x; 1.0825x over previous
//
#include <hip/hip_runtime.h>

// WindowAttention (Swin-style) on gfx950 — R4.
// R4 changes vs R3:
//   * gemm_qkv: LDS-staged coalesced epilogue (was: 64 scalar 2B scattered
//     stores/thread; V^T path was 2B stores at 128B stride). Stage acc into a
//     padded 128x136 bf16 LDS tile, then write out:
//       Q/K: 16B dwordx4 stores, exact 64B-line aligned.
//       V^T: 2B stores mapped along s (lanes contiguous in dst).
//   * XCD-bijective block swizzle on both GEMMs (same-A-panel tiles -> same XCD L2).
//   * zero_vpad: zero V^T pad rows s in [48,64) before gemm_qkv (P=0 x pad safety).
// ws layout (bytes): unchanged from R3.

typedef unsigned short u16;
typedef __attribute__((ext_vector_type(8))) short short8;
typedef __attribute__((ext_vector_type(4))) float floatx4;

#define B_WIN 2048
#define SEQ 49
#define DIM 512
#define NHEAD 16
#define HD 32
#define MROWS (B_WIN * SEQ)          // 100352
#define QTOT 51380224u               // 2048*16*49*32 elems (one Q or K plane set)
#define VOFF 102760448u              // elem offset of Vt planes ( = 2*QTOT)

__device__ __forceinline__ u16 f2bf(float x) {
    unsigned u = __float_as_uint(x);
    u += 0x7fffu + ((u >> 16) & 1u);   // RNE
    return (u16)(u >> 16);
}

__device__ __forceinline__ void async_ld16(const void* g, void* l) {
    __builtin_amdgcn_global_load_lds(
        (const __attribute__((address_space(1))) void*)g,
        (__attribute__((address_space(3))) void*)l, 16, 0, 0);
}

// ---------- conversion kernels ----------
__global__ void conv_f32_bf16(const float* __restrict__ in, u16* __restrict__ out, int n4) {
    int id = blockIdx.x * 256 + threadIdx.x;
    if (id >= n4) return;
    float4 v = ((const float4*)in)[id];
    uint2 o;
    o.x = (unsigned)f2bf(v.x) | ((unsigned)f2bf(v.y) << 16);
    o.y = (unsigned)f2bf(v.z) | ((unsigned)f2bf(v.w) << 16);
    *(uint2*)(out + (size_t)id * 4) = o;
}

// in: [512][Cn] f32 (k-major). out: [Cn][512] bf16 (n-major).
__global__ void transpose_conv(const float* __restrict__ in, u16* __restrict__ out, int Cn) {
    int id = blockIdx.x * 256 + threadIdx.x;
    if (id >= Cn * 512) return;
    int k = id & 511;
    int n = id >> 9;
    out[id] = f2bf(in[(size_t)k * Cn + n]);
}

// combined[w][h][i][j] = bias_table[rel_idx[i*49+j]][h] + mask[w][i][j]
__global__ void build_combined(const float* __restrict__ mask, const float* __restrict__ bias_table,
                               const int* __restrict__ rel_idx, float* __restrict__ cmb) {
    int id = blockIdx.x * 256 + threadIdx.x;    // 64*16*2401 = 2,458,624
    if (id >= 64 * 16 * 2401) return;
    int ij = id % 2401;
    int wh = id / 2401;
    int h = wh & 15, w = wh >> 4;
    cmb[id] = bias_table[rel_idx[ij] * NHEAD + h] + mask[(size_t)w * 2401 + ij];
}

// zero V^T pad region: elems s in [48,64) per (bh, d). gemm_qkv later rewrites s=48.
__global__ void zero_vpad(u16* __restrict__ qkvp) {
    int id = blockIdx.x * 256 + threadIdx.x;     // 2048*16*32 = 1,048,576
    if (id >= 2048 * 16 * 32) return;
    uint4 z = {0u, 0u, 0u, 0u};
    u16* p = qkvp + VOFF + (size_t)id * 64 + 48; // byte offset 96: 16B aligned
    *(uint4*)p = z;                               // elems 48..55
    *((uint4*)p + 1) = z;                         // elems 56..63
}

// ---------- GEMM1: qkv = x @ qkv_w + b, scattered to per-head planes ----------
__global__ __launch_bounds__(256, 2)
void gemm_qkv(const u16* __restrict__ A, const u16* __restrict__ Bt,
              const float* __restrict__ bias, u16* __restrict__ qkvp) {
    const int K = 512;
    const int tid  = threadIdx.x;
    const int lane = tid & 63, wave = tid >> 6;
    const int quad = lane >> 4, l16 = lane & 15;
    const int wr = wave >> 1, wc = wave & 1;

    // XCD-bijective swizzle: 9408 blocks = 8 * 1176. Consecutive HW ids (round-
    // robin across XCDs) map to swz = xcd*1176 + k, so each XCD processes
    // contiguous tiles; the 12 tiles sharing one A row-panel stay on one XCD L2.
    const int flat = blockIdx.y * 12 + blockIdx.x;
    const int swz  = (flat & 7) * 1176 + (flat >> 3);
    const int bx = swz % 12;
    const int by = swz / 12;
    const int m0 = by * 128, n0 = bx * 128;

    // K-loop: As = smem[0..4095], Bs = smem[4096..8191] (each 128x32 u16).
    // Epilogue: whole buffer reused as 128x136 bf16 stage (row pad 8 elems:
    // row stride 272B = 17*16B -> 16B-aligned rows for ds_read_b128).
    __shared__ u16 smem[128 * 136];
    u16* As = smem;
    u16* Bs = smem + 4096;

    const int f0 = (wave * 2 + 0) * 512 + lane * 8;
    const int f1 = (wave * 2 + 1) * 512 + lane * 8;
    const int r0 = f0 >> 5, c0 = f0 & 31;
    const int r1 = f1 >> 5, c1 = f1 & 31;
    const u16* Ab = A + (size_t)m0 * K;
    const u16* Bb = Bt + (size_t)n0 * K;

    floatx4 acc[4][4] = {};

    for (int kt = 0; kt < K; kt += 32) {
        async_ld16(Ab + (size_t)r0 * K + kt + c0, &As[f0]);
        async_ld16(Ab + (size_t)r1 * K + kt + c1, &As[f1]);
        async_ld16(Bb + (size_t)r0 * K + kt + c0, &Bs[f0]);
        async_ld16(Bb + (size_t)r1 * K + kt + c1, &Bs[f1]);
        __syncthreads();
        short8 af[4], bf[4];
#pragma unroll
        for (int i = 0; i < 4; ++i)
            af[i] = *(const short8*)&As[(wr * 64 + i * 16 + l16) * 32 + quad * 8];
#pragma unroll
        for (int j = 0; j < 4; ++j)
            bf[j] = *(const short8*)&Bs[(wc * 64 + j * 16 + l16) * 32 + quad * 8];
#pragma unroll
        for (int i = 0; i < 4; ++i)
#pragma unroll
            for (int j = 0; j < 4; ++j)
                acc[i][j] = __builtin_amdgcn_mfma_f32_16x16x32_bf16(af[i], bf[j], acc[i][j], 0, 0, 0);
        __syncthreads();
    }

    // ---- epilogue phase A: acc (+bias) -> bf16 into padded LDS stage ----
    // (loop's trailing __syncthreads guarantees no wave still reads As/Bs)
#pragma unroll
    for (int j = 0; j < 4; ++j) {
        const int col = wc * 64 + j * 16 + l16;
        const float bv = bias[n0 + col];
#pragma unroll
        for (int i = 0; i < 4; ++i)
#pragma unroll
            for (int r = 0; r < 4; ++r) {
                const int row = wr * 64 + i * 16 + quad * 4 + r;
                smem[row * 136 + col] = f2bf(acc[i][j][r] + bv);
            }
    }
    __syncthreads();

    // ---- epilogue phase B: cooperative coalesced writeout ----
    if (n0 < 1024) {
        // Q or K planes: [bh][49][32]. 128 rows x 4 head-blocks x 4 parts of 16B.
        // Consecutive (part) threads write one full 64B line (dst 64B-aligned:
        // bh*3136B + s*64B + part*16B).
        const int c   = n0 >> 9;
        const int hh0 = (n0 & 511) >> 5;
        u16* base = qkvp + (size_t)c * QTOT;
#pragma unroll
        for (int it = 0; it < 8; ++it) {
            const int idx  = it * 256 + tid;      // 0..2047
            const int row  = idx >> 4;
            const int hb   = (idx >> 2) & 3;
            const int part = idx & 3;
            short8 v = *(const short8*)&smem[row * 136 + hb * 32 + part * 8];
            const int rg = m0 + row;
            const int b2 = (int)((unsigned)rg / 49u);
            const int s  = rg - b2 * 49;
            *(short8*)(base + (size_t)(b2 * 16 + hh0 + hb) * 1568 + s * 32 + part * 8) = v;
        }
    } else {
        // V^T planes: [bh][32 d][64 s]. Map lanes along s: consecutive threads ->
        // consecutive rows (s) -> contiguous 98B runs per window in dst.
        const int hh0 = (n0 - 1024) >> 5;
        u16* base = qkvp + VOFF;
#pragma unroll 16
        for (int it = 0; it < 64; ++it) {
            const int idx = it * 256 + tid;       // 0..16383
            const int col = idx >> 7;             // 0..127 (tile col = head*32+d)
            const int row = idx & 127;
            const u16 v = smem[row * 136 + col];
            const int rg = m0 + row;
            const int b2 = (int)((unsigned)rg / 49u);
            const int s  = rg - b2 * 49;
            const int hh = hh0 + (col >> 5);
            const int d  = col & 31;
            base[(size_t)(b2 * 16 + hh) * 2048 + d * 64 + s] = v;
        }
    }
}

// ---------- GEMM: C[M][N] = A[M][K](bf16) * Bt[N][K]^T + bias (f32 out) ----------
__global__ __launch_bounds__(256, 2)
void gemm_bt(const u16* __restrict__ A, const u16* __restrict__ Bt,
             const float* __restrict__ bias, float* __restrict__ Cout,
             int M, int N, int K) {
    const int tid  = threadIdx.x;
    const int lane = tid & 63, wave = tid >> 6;
    const int quad = lane >> 4, l16 = lane & 15;
    const int wr = wave >> 1, wc = wave & 1;

    // XCD-bijective swizzle (generic: only applied when grid divides by 8).
    const int nbx = gridDim.x, nby = gridDim.y;
    const int total = nbx * nby;
    const int flat = blockIdx.y * nbx + blockIdx.x;
    const int swz = ((total & 7) == 0) ? ((flat & 7) * (total >> 3) + (flat >> 3)) : flat;
    const int bx = swz % nbx;
    const int by = swz / nbx;
    const int m0 = by * 128, n0 = bx * 128;

    __shared__ u16 As[128 * 32];
    __shared__ u16 Bs[128 * 32];

    const int f0 = (wave * 2 + 0) * 512 + lane * 8;
    const int f1 = (wave * 2 + 1) * 512 + lane * 8;
    const int r0 = f0 >> 5, c0 = f0 & 31;
    const int r1 = f1 >> 5, c1 = f1 & 31;
    const u16* Ab = A + (size_t)m0 * K;
    const u16* Bb = Bt + (size_t)n0 * K;

    floatx4 acc[4][4] = {};

    for (int kt = 0; kt < K; kt += 32) {
        async_ld16(Ab + (size_t)r0 * K + kt + c0, &As[f0]);
        async_ld16(Ab + (size_t)r1 * K + kt + c1, &As[f1]);
        async_ld16(Bb + (size_t)r0 * K + kt + c0, &Bs[f0]);
        async_ld16(Bb + (size_t)r1 * K + kt + c1, &Bs[f1]);
        __syncthreads();
        short8 af[4], bf[4];
#pragma unroll
        for (int i = 0; i < 4; ++i)
            af[i] = *(const short8*)&As[(wr * 64 + i * 16 + l16) * 32 + quad * 8];
#pragma unroll
        for (int j = 0; j < 4; ++j)
            bf[j] = *(const short8*)&Bs[(wc * 64 + j * 16 + l16) * 32 + quad * 8];
#pragma unroll
        for (int i = 0; i < 4; ++i)
#pragma unroll
            for (int j = 0; j < 4; ++j)
                acc[i][j] = __builtin_amdgcn_mfma_f32_16x16x32_bf16(af[i], bf[j], acc[i][j], 0, 0, 0);
        __syncthreads();
    }

#pragma unroll
    for (int i = 0; i < 4; ++i) {
#pragma unroll
        for (int j = 0; j < 4; ++j) {
            int col = n0 + wc * 64 + j * 16 + l16;
            float bv = bias[col];
#pragma unroll
            for (int r = 0; r < 4; ++r) {
                int row = m0 + wr * 64 + i * 16 + quad * 4 + r;
                Cout[(size_t)row * N + col] = acc[i][j][r] + bv;
            }
        }
    }
}

// ---------- attention: one wave per (b,h); direct global frags + register softmax ----------
__global__ __launch_bounds__(64, 4)
void attn2(const u16* __restrict__ qkvp, const float* __restrict__ cmb,
           u16* __restrict__ out) {
    const int bid = blockIdx.x;
    const int b = bid >> 4, h = bid & 15;
    const int lane = threadIdx.x;
    const int quad = lane >> 4, l16 = lane & 15;

    const u16* qb = qkvp + (size_t)(b * 16 + h) * 1568;
    const u16* kb = qb + QTOT;
    const u16* vb = qkvp + VOFF + (size_t)(b * 16 + h) * 2048;   // V^T [32][64]

    __shared__ u16 ps[64 * 72];        // probs, row stride 72 elems (144 B)

    short8 af[4], bfr[4];
#pragma unroll
    for (int i = 0; i < 4; ++i) {
        int r = i * 16 + l16; if (r > 48) r = 48;     // clamp pad rows (outputs discarded)
        af[i] = *(const short8*)(qb + r * 32 + quad * 8);
    }
#pragma unroll
    for (int j = 0; j < 4; ++j) {
        int n = j * 16 + l16; if (n > 48) n = 48;     // clamp pad cols (logits masked)
        bfr[j] = *(const short8*)(kb + n * 32 + quad * 8);
    }

    const float scale = 0.1767766952966369f;          // 32^-0.5
    const float* cb = cmb + (size_t)((b & 63) * 16 + h) * 2401;

#pragma unroll
    for (int i = 0; i < 4; ++i) {
        floatx4 accS[4] = {};
#pragma unroll
        for (int j = 0; j < 4; ++j)
            accS[j] = __builtin_amdgcn_mfma_f32_16x16x32_bf16(af[i], bfr[j], accS[j], 0, 0, 0);
        const int rbase = i * 16 + quad * 4;
#pragma unroll
        for (int r = 0; r < 4; ++r) {
            int row = rbase + r;
            int rc = row < 48 ? row : 48;             // keep table reads in bounds
            float x[4];
#pragma unroll
            for (int j = 0; j < 4; ++j) {
                int col = j * 16 + l16;
                x[j] = (col < SEQ) ? accS[j][r] * scale + cb[rc * 49 + col] : -3.0e38f;
            }
            float m = fmaxf(fmaxf(x[0], x[1]), fmaxf(x[2], x[3]));
#pragma unroll
            for (int off = 1; off < 16; off <<= 1) m = fmaxf(m, __shfl_xor(m, off));
            float e[4], s = 0.f;
#pragma unroll
            for (int j = 0; j < 4; ++j) { e[j] = __expf(x[j] - m); s += e[j]; }
#pragma unroll
            for (int off = 1; off < 16; off <<= 1) s += __shfl_xor(s, off);
            float inv = __builtin_amdgcn_rcpf(s);
#pragma unroll
            for (int j = 0; j < 4; ++j)
                ps[row * 72 + j * 16 + l16] = f2bf(e[j] * inv);
        }
    }
    __syncthreads();

    // PV: O[64x32] = P[64x64] * V[64x32] via A=ps rows, B=V^T rows
    floatx4 accO[4][2] = {};
#pragma unroll
    for (int kt = 0; kt < 2; ++kt) {
        short8 pf[4], vf[2];
#pragma unroll
        for (int i = 0; i < 4; ++i)
            pf[i] = *(const short8*)&ps[(i * 16 + l16) * 72 + kt * 32 + quad * 8];
#pragma unroll
        for (int jn = 0; jn < 2; ++jn)
            vf[jn] = *(const short8*)(vb + (jn * 16 + l16) * 64 + kt * 32 + quad * 8);
#pragma unroll
        for (int i = 0; i < 4; ++i)
#pragma unroll
            for (int jn = 0; jn < 2; ++jn)
                accO[i][jn] = __builtin_amdgcn_mfma_f32_16x16x32_bf16(pf[i], vf[jn], accO[i][jn], 0, 0, 0);
    }

    u16* op = out + (size_t)b * SEQ * DIM + h * HD;
#pragma unroll
    for (int i = 0; i < 4; ++i)
#pragma unroll
        for (int jn = 0; jn < 2; ++jn)
#pragma unroll
            for (int r = 0; r < 4; ++r) {
                int row = i * 16 + quad * 4 + r;
                if (row < SEQ)
                    op[(size_t)row * DIM + jn * 16 + l16] = f2bf(accO[i][jn][r]);
            }
}

extern "C" void kernel_launch(void* const* d_in, const int* in_sizes, int n_in,
                              void* d_out, int out_size, void* d_ws, size_t ws_size,
                              hipStream_t stream) {
    const float* x         = (const float*)d_in[0];
    const float* mask      = (const float*)d_in[1];
    const float* qkv_w     = (const float*)d_in[2];
    const float* qkv_b     = (const float*)d_in[3];
    const float* proj_w    = (const float*)d_in[4];
    const float* proj_b    = (const float*)d_in[5];
    const float* bias_tab  = (const float*)d_in[6];
    const int*   rel_idx   = (const int*)d_in[7];
    float* out = (float*)d_out;

    char* ws = (char*)d_ws;
    u16*   xbf     = (u16*)(ws + 0);               // reused as attn_out
    u16*   qkvp    = (u16*)(ws + 102760448);
    float* cmb     = (float*)(ws + 442499072);
    u16*   wqkv_t  = (u16*)(ws + 452333568);
    u16*   wproj_t = (u16*)(ws + 453906432);

    // x -> bf16 (51,380,224 elems = 12,845,056 float4s)
    conv_f32_bf16<<<50176, 256, 0, stream>>>(x, xbf, 12845056);
    // weight transposes
    transpose_conv<<<3072, 256, 0, stream>>>(qkv_w, wqkv_t, 1536);
    transpose_conv<<<1024, 256, 0, stream>>>(proj_w, wproj_t, 512);
    // combined bias+mask table
    build_combined<<<9604, 256, 0, stream>>>(mask, bias_tab, rel_idx, cmb);
    // zero V^T pad rows (s in [48,64)) before gemm_qkv rewrites s=48
    zero_vpad<<<4096, 256, 0, stream>>>(qkvp);
    // qkv GEMM -> scattered per-head planes (LDS-staged coalesced epilogue)
    gemm_qkv<<<dim3(12, 784), 256, 0, stream>>>(xbf, wqkv_t, qkv_b, qkvp);
    // attention -> attn_out (reuses xbf)
    attn2<<<B_WIN * NHEAD, 64, 0, stream>>>(qkvp, cmb, xbf);
    // out = attn @ proj_w + proj_b
    gemm_bt<<<dim3(4, 784), 256, 0, stream>>>(xbf, wproj_t, proj_b, out,
                                              MROWS, 512, 512);
}